// Round 1
// baseline (1558.511 us; speedup 1.0000x reference)
//
#include <hip/hip_runtime.h>
#include <math.h>

namespace {

constexpr int Bb = 8, Ll = 1024, Dd = 768, Hh = 12, DHh = 64;
constexpr float MAXN = 1.0f - 1e-5f;
constexpr float EPSf = 1e-15f;

__device__ __forceinline__ float wred64(float v) {
#pragma unroll
  for (int m = 32; m >= 1; m >>= 1) v += __shfl_xor(v, m, 64);
  return v;
}

__device__ __forceinline__ float artanh_(float x) {
  return 0.5f * logf((1.0f + x) / (1.0f - x));
}

// ---------------------------------------------------------------------------
// Generic tiled f32 GEMM: C = A @ Bw^T, A (M=8192, K=768) row-major,
// Bw (N=768, K=768) row-major. blockIdx.z selects among 3 (B, C) pairs.
// 64x64 tile, 256 threads, 4x4 register tile, BK=32, transposed LDS.
// ---------------------------------------------------------------------------
__global__ __launch_bounds__(256) void k_gemm3(
    const float* __restrict__ A,
    const float* __restrict__ B0, const float* __restrict__ B1,
    const float* __restrict__ B2,
    float* __restrict__ C0, float* __restrict__ C1p, float* __restrict__ C2p) {
  constexpr int K = Dd, N = Dd;
  const float* Bw = (blockIdx.z == 0) ? B0 : (blockIdx.z == 1 ? B1 : B2);
  float* C = (blockIdx.z == 0) ? C0 : (blockIdx.z == 1 ? C1p : C2p);
  __shared__ __align__(16) float As[32][68];  // [k][m]
  __shared__ __align__(16) float Bs[32][68];  // [k][n]
  const int t = threadIdx.x;
  const int tx = t & 15, ty = t >> 4;
  const int m0 = blockIdx.y * 64, n0 = blockIdx.x * 64;
  const int lc = t & 31, lr0 = t >> 5;
  float acc[4][4] = {};
  for (int k0 = 0; k0 < K; k0 += 32) {
    __syncthreads();
#pragma unroll
    for (int i = 0; i < 8; i++) {
      const int r = lr0 + i * 8;
      As[lc][r] = A[(size_t)(m0 + r) * K + k0 + lc];
      Bs[lc][r] = Bw[(size_t)(n0 + r) * K + k0 + lc];
    }
    __syncthreads();
#pragma unroll 16
    for (int kk = 0; kk < 32; kk++) {
      float a[4], b[4];
      *(float4*)a = *(const float4*)&As[kk][ty * 4];
      *(float4*)b = *(const float4*)&Bs[kk][tx * 4];
#pragma unroll
      for (int i = 0; i < 4; i++)
#pragma unroll
        for (int j = 0; j < 4; j++)
          acc[i][j] = fmaf(a[i], b[j], acc[i][j]);
    }
  }
#pragma unroll
  for (int i = 0; i < 4; i++) {
    float4 v = make_float4(acc[i][0], acc[i][1], acc[i][2], acc[i][3]);
    *(float4*)&C[(size_t)(m0 + ty * 4 + i) * N + n0 + tx * 4] = v;
  }
}

// ---------------------------------------------------------------------------
// Per-row: finish mobius_matvec (tanh scaling + project), logmap0, beta-split
// into heads with expmap0. One block = one (b,l) row, 768 threads,
// wave w == head w (64 lanes == DH).
// Also caches per-head squared norms (q2/k2) and lam (for v).
// ---------------------------------------------------------------------------
__global__ __launch_bounds__(768) void k_qkv_transform(
    const float* __restrict__ x,
    const float* __restrict__ mq, const float* __restrict__ mk,
    const float* __restrict__ mv,
    float* __restrict__ qh, float* __restrict__ kh, float* __restrict__ vhl,
    float* __restrict__ q2n, float* __restrict__ k2n,
    float* __restrict__ lam1, float beta_ratio) {
  const int t = threadIdx.x;
  const int row = blockIdx.x;  // b*L + l
  const int b = row >> 10, l = row & 1023;
  const int w = t >> 6, lane = t & 63;
  __shared__ float red[12];

  const float xe = x[(size_t)row * Dd + t];
  float s = wred64(xe * xe);
  if (lane == 0) red[w] = s;
  __syncthreads();
  float xn2 = 0.0f;
#pragma unroll
  for (int i = 0; i < 12; i++) xn2 += red[i];
  const float xn = sqrtf(fmaxf(xn2, EPSf * EPSf));
  const float arx = artanh_(fminf(xn, MAXN));

  const float* mptr[3] = {mq, mk, mv};
#pragma unroll
  for (int mi = 0; mi < 3; mi++) {
    const float me = mptr[mi][(size_t)row * Dd + t];
    __syncthreads();  // protect red reuse
    float s2 = wred64(me * me);
    if (lane == 0) red[w] = s2;
    __syncthreads();
    float mn2 = 0.0f;
#pragma unroll
    for (int i = 0; i < 12; i++) mn2 += red[i];
    const float mxn = sqrtf(fmaxf(mn2, EPSf * EPSf));
    const float pn = tanhf(mxn / xn * arx);
    // mobius_matvec scale incl. project
    const float c1 = pn / mxn * fminf(1.0f, MAXN / fmaxf(pn, EPSf));
    // logmap0 of projected point (norm = min(pn, MAXN))
    const float nn = fmaxf(fminf(pn, MAXN), EPSf);
    const float c2 = artanh_(nn) / nn;
    const float ve = c2 * c1 * me * beta_ratio;  // per-head tangent element
    const float hs = wred64(ve * ve);            // per-head (wave) sumsq
    const float hn = sqrtf(fmaxf(hs, EPSf * EPSf));
    const float th = tanhf(hn);
    const float oe = th / hn * ve;  // expmap0 head point element
    const size_t hidx = (size_t)(b * Hh + w) * Ll + l;
    const size_t oidx = hidx * DHh + lane;
    if (mi == 0) {
      qh[oidx] = oe;
      if (lane == 0) q2n[hidx] = th * th;
    } else if (mi == 1) {
      kh[oidx] = oe;
      if (lane == 0) k2n[hidx] = th * th;
    } else {
      const float lam = 2.0f / fmaxf(1.0f - th * th, EPSf);
      vhl[oidx] = lam * oe;
      if (lane == 0) lam1[hidx] = lam - 1.0f;
    }
  }
}

// ---------------------------------------------------------------------------
// Scores: per (b,h), 64 q-rows per block, stream k in chunks of 64.
// e = exp(-scale * dist) written UNNORMALIZED to attn; row sums to ws.
// dist = 2 artanh(t), exp(-s*2*artanh(t)) = ((1-t)/(1+t))^s.
// ---------------------------------------------------------------------------
__global__ __launch_bounds__(256) void k_scores(
    const float* __restrict__ qh, const float* __restrict__ kh,
    const float* __restrict__ q2n, const float* __restrict__ k2n,
    const float* __restrict__ scale_p,
    float* __restrict__ attn, float* __restrict__ rowsum) {
  __shared__ __align__(16) float Qs[64][68];  // [d][q]
  __shared__ __align__(16) float Ks[64][68];  // [d][k]
  __shared__ float q2s[64], k2s[64];
  const int t = threadIdx.x;
  const int tx = t & 15, ty = t >> 4;
  const int bh = blockIdx.y;
  const int q0 = blockIdx.x * 64;
  const float scale = scale_p[0];
  const size_t hbase = (size_t)bh * Ll;

  {
    const int d = t & 63, rw = t >> 6;
#pragma unroll
    for (int i = 0; i < 16; i++) {
      const int r = (i << 2) + rw;
      Qs[d][r] = qh[(hbase + q0 + r) * DHh + d];
    }
  }
  if (t < 64) q2s[t] = q2n[hbase + q0 + t];

  float rs[4] = {0.0f, 0.0f, 0.0f, 0.0f};
  for (int c = 0; c < 16; c++) {
    __syncthreads();
    {
      const int d = t & 63, rw = t >> 6;
#pragma unroll
      for (int i = 0; i < 16; i++) {
        const int r = (i << 2) + rw;
        Ks[d][r] = kh[(hbase + c * 64 + r) * DHh + d];
      }
      if (t < 64) k2s[t] = k2n[hbase + c * 64 + t];
    }
    __syncthreads();
    float acc[4][4] = {};
#pragma unroll 16
    for (int d = 0; d < 64; d++) {
      float a[4], b[4];
      *(float4*)a = *(const float4*)&Qs[d][ty * 4];
      *(float4*)b = *(const float4*)&Ks[d][tx * 4];
#pragma unroll
      for (int i = 0; i < 4; i++)
#pragma unroll
        for (int j = 0; j < 4; j++)
          acc[i][j] = fmaf(a[i], b[j], acc[i][j]);
    }
#pragma unroll
    for (int i = 0; i < 4; i++) {
      const float q2v = q2s[ty * 4 + i];
      float ev[4];
#pragma unroll
      for (int j = 0; j < 4; j++) {
        const float k2v = k2s[tx * 4 + j];
        const float qk = acc[i][j];
        const float diff2 = fmaxf(q2v + k2v - 2.0f * qk, 0.0f);
        const float den = fmaxf(1.0f - 2.0f * qk + q2v * k2v, EPSf);
        float tt = sqrtf(fmaxf(diff2 / den, 0.0f));
        tt = fminf(tt, MAXN);
        const float e = expf(scale * logf((1.0f - tt) / (1.0f + tt)));
        ev[j] = e;
        rs[i] += e;
      }
      *(float4*)&attn[(hbase + q0 + ty * 4 + i) * Ll + c * 64 + tx * 4] =
          *(float4*)ev;
    }
  }
#pragma unroll
  for (int i = 0; i < 4; i++) {
    float v = rs[i];
    v += __shfl_xor(v, 1, 64);
    v += __shfl_xor(v, 2, 64);
    v += __shfl_xor(v, 4, 64);
    v += __shfl_xor(v, 8, 64);
    if (tx == 0) rowsum[hbase + q0 + ty * 4 + i] = v;
  }
}

// ---------------------------------------------------------------------------
// Midpoint: normalize attn in place, PV GEMM with lam*v and lam-1,
// then mobius_scalar_mul(0.5) + project. Writes yh in (B,L,H,DH) layout.
// ---------------------------------------------------------------------------
__global__ __launch_bounds__(256) void k_midpoint(
    float* __restrict__ attn, const float* __restrict__ vhl,
    const float* __restrict__ lam1, const float* __restrict__ rowsum,
    float* __restrict__ yh) {
  __shared__ __align__(16) float Ws[64][68];  // [k][q] normalized weights
  __shared__ __align__(16) float Ls[64][68];  // [k][d] lam*v
  __shared__ float l1s[64];
  __shared__ float rinv[64];
  const int t = threadIdx.x;
  const int tx = t & 15, ty = t >> 4;
  const int bh = blockIdx.y;
  const int b = bh / Hh, h = bh % Hh;
  const int q0 = blockIdx.x * 64;
  const size_t hbase = (size_t)bh * Ll;
  if (t < 64) rinv[t] = 1.0f / rowsum[hbase + q0 + t];

  float acc[4][4] = {};
  float dacc[4] = {0.0f, 0.0f, 0.0f, 0.0f};
  for (int c = 0; c < 16; c++) {
    __syncthreads();
    {
      const int d = t & 63, rw = t >> 6;
#pragma unroll
      for (int i = 0; i < 16; i++) {
        const int k = (i << 2) + rw;
        Ls[k][d] = vhl[(hbase + c * 64 + k) * DHh + d];
      }
      if (t < 64) l1s[t] = lam1[hbase + c * 64 + t];
#pragma unroll
      for (int i = 0; i < 16; i++) {
        const int q = (i << 2) + rw;
        const size_t gidx = (hbase + q0 + q) * Ll + c * 64 + d;
        const float wv = attn[gidx] * rinv[q];
        attn[gidx] = wv;  // final normalized attention output
        Ws[d][q] = wv;
      }
    }
    __syncthreads();
#pragma unroll 16
    for (int k = 0; k < 64; k++) {
      float a[4], bb[4];
      *(float4*)a = *(const float4*)&Ws[k][ty * 4];
      *(float4*)bb = *(const float4*)&Ls[k][tx * 4];
      const float l1 = l1s[k];
#pragma unroll
      for (int i = 0; i < 4; i++) {
        dacc[i] = fmaf(a[i], l1, dacc[i]);
#pragma unroll
        for (int j = 0; j < 4; j++)
          acc[i][j] = fmaf(a[i], bb[j], acc[i][j]);
      }
    }
  }
#pragma unroll
  for (int i = 0; i < 4; i++) {
    float den = dacc[i];
    if (fabsf(den) < 1e-10f) den = 1e-10f;
    const float dinv = 1.0f / den;
    float tm[4];
    float n2p = 0.0f;
#pragma unroll
    for (int j = 0; j < 4; j++) {
      tm[j] = acc[i][j] * dinv;
      n2p += tm[j] * tm[j];
    }
    n2p += __shfl_xor(n2p, 1, 64);
    n2p += __shfl_xor(n2p, 2, 64);
    n2p += __shfl_xor(n2p, 4, 64);
    n2p += __shfl_xor(n2p, 8, 64);
    const float n = sqrtf(fmaxf(n2p, EPSf * EPSf));
    const float ar = artanh_(fminf(n, MAXN));
    const float pn = tanhf(0.5f * ar);
    const float f = pn / n * fminf(1.0f, MAXN / fmaxf(pn, EPSf));
    float ov[4];
#pragma unroll
    for (int j = 0; j < 4; j++) ov[j] = f * tm[j];
    const int l = q0 + ty * 4 + i;
    *(float4*)&yh[((size_t)(b * Ll + l) * Hh + h) * DHh + tx * 4] =
        *(float4*)ov;
  }
}

// ---------------------------------------------------------------------------
// beta_concat: per-head logmap0 / BETA_RATIO, then expmap0 over full D.
// ---------------------------------------------------------------------------
__global__ __launch_bounds__(768) void k_concat(
    const float* __restrict__ yh, float* __restrict__ yc, float beta_ratio) {
  const int t = threadIdx.x;
  const int row = blockIdx.x;
  const int w = t >> 6, lane = t & 63;
  __shared__ float red[12];
  const float ye = yh[(size_t)row * Dd + t];
  const float hs = wred64(ye * ye);
  const float hn = sqrtf(fmaxf(hs, EPSf * EPSf));
  const float cc = artanh_(fminf(hn, MAXN)) / hn / beta_ratio;
  const float ve = cc * ye;
  const float s = wred64(ve * ve);
  if (lane == 0) red[w] = s;
  __syncthreads();
  float n2 = 0.0f;
#pragma unroll
  for (int i = 0; i < 12; i++) n2 += red[i];
  const float n = sqrtf(fmaxf(n2, EPSf * EPSf));
  const float f = tanhf(n) / n;
  yc[(size_t)row * Dd + t] = f * ve;
}

// ---------------------------------------------------------------------------
// Final: mobius_matvec scaling (project), mobius_add with bias, project.
// ---------------------------------------------------------------------------
__global__ __launch_bounds__(768) void k_final(
    const float* __restrict__ yc, const float* __restrict__ mp,
    const float* __restrict__ bp, float* __restrict__ out) {
  const int t = threadIdx.x;
  const int row = blockIdx.x;
  const int w = t >> 6, lane = t & 63;
  __shared__ float red[12];
  auto blockSum = [&](float v) -> float {
    __syncthreads();  // protect red reuse
    const float s = wred64(v);
    if (lane == 0) red[w] = s;
    __syncthreads();
    float tot = 0.0f;
#pragma unroll
    for (int i = 0; i < 12; i++) tot += red[i];
    return tot;
  };
  const float xe = yc[(size_t)row * Dd + t];
  const float me = mp[(size_t)row * Dd + t];
  const float be = bp[t];
  const float xn2 = blockSum(xe * xe);
  const float xn = sqrtf(fmaxf(xn2, EPSf * EPSf));
  const float arx = artanh_(fminf(xn, MAXN));
  const float mn2 = blockSum(me * me);
  const float mxn = sqrtf(fmaxf(mn2, EPSf * EPSf));
  const float pn = tanhf(mxn / xn * arx);
  const float c1 = pn / mxn * fminf(1.0f, MAXN / fmaxf(pn, EPSf));
  const float mme = c1 * me;  // projected mobius_matvec result
  const float x2 = blockSum(mme * mme);
  const float y2 = blockSum(be * be);
  const float xy = blockSum(mme * be);
  const float nume = (1.0f + 2.0f * xy + y2) * mme + (1.0f - x2) * be;
  const float den = fmaxf(1.0f + 2.0f * xy + x2 * y2, EPSf);
  const float re = nume / den;
  const float rn2 = blockSum(re * re);
  const float rn = sqrtf(fmaxf(rn2, EPSf * EPSf));
  const float f = fminf(1.0f, MAXN / rn);
  out[(size_t)row * Dd + t] = f * re;
}

}  // namespace

extern "C" void kernel_launch(void* const* d_in, const int* in_sizes, int n_in,
                              void* d_out, int out_size, void* d_ws,
                              size_t ws_size, hipStream_t stream) {
  const float* x = (const float*)d_in[0];
  const float* Wq = (const float*)d_in[1];
  const float* Wk = (const float*)d_in[2];
  const float* Wv = (const float*)d_in[3];
  const float* Wp = (const float*)d_in[4];
  const float* bp = (const float*)d_in[5];
  const float* scale = (const float*)d_in[6];

  float* out = (float*)d_out;
  float* y_out = out;                                // (B,L,D)
  float* attn = out + (size_t)Bb * Ll * Dd;          // (B,H,L,L)

  const size_t NH = (size_t)Bb * Hh * Ll;            // 98304
  const size_t RD = (size_t)Bb * Ll * Dd;            // 6291456
  float* ws = (float*)d_ws;
  float* qh = ws;               // NH*DH
  float* kh = qh + RD;          // NH*DH == RD
  float* vhl = kh + RD;         // lam * v
  float* yh = vhl + RD;         // midpoint result, (B,L,H,DH)
  float* rowsum = yh + RD;      // NH
  float* q2n = rowsum + NH;     // NH
  float* k2n = q2n + NH;        // NH
  float* lam1 = k2n + NH;       // NH
  float* yc = qh;               // reuse (qh dead after k_scores)
  float* mp = kh;               // reuse (kh dead after k_scores)

  // GEMM outputs staged in the (not yet written) attn region of d_out.
  float* mq = attn;
  float* mk = attn + RD;
  float* mv = attn + 2 * RD;

  const double br =
      exp(lgamma(DHh / 2.0) + lgamma(0.5) - lgamma(DHh / 2.0 + 0.5) -
          (lgamma(Dd / 2.0) + lgamma(0.5) - lgamma(Dd / 2.0 + 0.5)));
  const float beta_ratio = (float)br;

  (void)in_sizes; (void)n_in; (void)out_size; (void)ws_size;

  dim3 g1(Dd / 64, (Bb * Ll) / 64, 3);
  k_gemm3<<<g1, dim3(256), 0, stream>>>(x, Wq, Wk, Wv, mq, mk, mv);

  k_qkv_transform<<<dim3(Bb * Ll), dim3(768), 0, stream>>>(
      x, mq, mk, mv, qh, kh, vhl, q2n, k2n, lam1, beta_ratio);

  k_scores<<<dim3(16, Bb * Hh), dim3(256), 0, stream>>>(
      qh, kh, q2n, k2n, scale, attn, rowsum);

  k_midpoint<<<dim3(16, Bb * Hh), dim3(256), 0, stream>>>(
      attn, vhl, lam1, rowsum, yh);

  k_concat<<<dim3(Bb * Ll), dim3(768), 0, stream>>>(yh, yc, beta_ratio);

  dim3 g2(Dd / 64, (Bb * Ll) / 64, 1);
  k_gemm3<<<g2, dim3(256), 0, stream>>>(yc, Wp, Wp, Wp, mp, mp, mp);

  k_final<<<dim3(Bb * Ll), dim3(768), 0, stream>>>(yc, mp, bp, y_out);
}

// Round 2
// 1150.386 us; speedup vs baseline: 1.3548x; 1.3548x over previous
//
#include <hip/hip_runtime.h>
#include <hip/hip_bf16.h>
#include <math.h>

namespace {

constexpr int Bb = 8, Ll = 1024, Dd = 768, Hh = 12, DHh = 64;
constexpr int DDm = Dd * Dd;
constexpr float MAXN = 1.0f - 1e-5f;
constexpr float EPSf = 1e-15f;

typedef __attribute__((ext_vector_type(8))) short short8;
typedef __attribute__((ext_vector_type(4))) float f32x4;

__device__ __forceinline__ float wred64(float v) {
#pragma unroll
  for (int m = 32; m >= 1; m >>= 1) v += __shfl_xor(v, m, 64);
  return v;
}

__device__ __forceinline__ float artanh_(float x) {
  return 0.5f * logf((1.0f + x) / (1.0f - x));
}

// ---------------------------------------------------------------------------
// Split fp32 -> bf16 hi + bf16 lo (x ~= hi + lo).
// ---------------------------------------------------------------------------
__global__ __launch_bounds__(256) void k_cvt(const float* __restrict__ in,
                                             unsigned short* __restrict__ hi,
                                             unsigned short* __restrict__ lo,
                                             int n4) {
  const int i = blockIdx.x * 256 + threadIdx.x;
  if (i >= n4) return;
  float4 v = ((const float4*)in)[i];
  ushort4 h, l;
  float xs[4] = {v.x, v.y, v.z, v.w};
  unsigned short hs[4], ls[4];
#pragma unroll
  for (int j = 0; j < 4; j++) {
    const float x = xs[j];
    __hip_bfloat16 hb = __float2bfloat16(x);
    const float hf = __bfloat162float(hb);
    __hip_bfloat16 lb = __float2bfloat16(x - hf);
    hs[j] = *(unsigned short*)&hb;
    ls[j] = *(unsigned short*)&lb;
  }
  h = make_ushort4(hs[0], hs[1], hs[2], hs[3]);
  l = make_ushort4(ls[0], ls[1], ls[2], ls[3]);
  ((ushort4*)hi)[i] = h;
  ((ushort4*)lo)[i] = l;
}

// ---------------------------------------------------------------------------
// bf16-split MFMA GEMM: C = A @ W^T in ~fp32 precision.
// A (8192,768) as hi/lo bf16, W (768,768) row-major as hi/lo bf16,
// blockIdx.z selects W + z*DD and C + z*8192*768.
// 128x128 tile, 256 threads (4 waves, 2x2), BK=32, mfma 16x16x32,
// XOR quad-slot swizzled LDS (conflict-minimum b128 read/write).
// ---------------------------------------------------------------------------
__global__ __launch_bounds__(256) void k_gemm_bf16s(
    const unsigned short* __restrict__ Ahi, const unsigned short* __restrict__ Alo,
    const unsigned short* __restrict__ Whi, const unsigned short* __restrict__ Wlo,
    float* __restrict__ C) {
  constexpr int K = Dd, N = Dd;
  const int z = blockIdx.z;
  const unsigned short* Bh = Whi + (size_t)z * DDm;
  const unsigned short* Bl = Wlo + (size_t)z * DDm;
  float* Cz = C + (size_t)z * 8192 * N;
  __shared__ __align__(16) unsigned short sAh[128 * 32];
  __shared__ __align__(16) unsigned short sAl[128 * 32];
  __shared__ __align__(16) unsigned short sBh[128 * 32];
  __shared__ __align__(16) unsigned short sBl[128 * 32];
  const int t = threadIdx.x;
  const int l = t & 63, wid = t >> 6;
  const int wr = wid >> 1, wc = wid & 1;
  const int m0 = blockIdx.y * 128, n0 = blockIdx.x * 128;

  // staging: 512 chunks of 8 bf16; thread handles chunks t and t+256
  const int r0 = t >> 2, kf0 = t & 3;
  const int r1 = (t + 256) >> 2, kf1 = (t + 256) & 3;
  const int sw0 = r0 * 32 + ((kf0 ^ ((r0 >> 1) & 3)) << 3);
  const int sw1 = r1 * 32 + ((kf1 ^ ((r1 >> 1) & 3)) << 3);
  const size_t ga0 = (size_t)(m0 + r0) * K + kf0 * 8;
  const size_t ga1 = (size_t)(m0 + r1) * K + kf1 * 8;
  const size_t gb0 = (size_t)(n0 + r0) * K + kf0 * 8;
  const size_t gb1 = (size_t)(n0 + r1) * K + kf1 * 8;

  const int lar = l & 15, lkf = l >> 4;

  f32x4 acc[4][4] = {};

  for (int k0 = 0; k0 < K; k0 += 32) {
    // issue global loads early (registers only — safe before barrier)
    const short8 vah0 = *(const short8*)&Ahi[ga0 + k0];
    const short8 vah1 = *(const short8*)&Ahi[ga1 + k0];
    const short8 val0 = *(const short8*)&Alo[ga0 + k0];
    const short8 val1 = *(const short8*)&Alo[ga1 + k0];
    const short8 vbh0 = *(const short8*)&Bh[gb0 + k0];
    const short8 vbh1 = *(const short8*)&Bh[gb1 + k0];
    const short8 vbl0 = *(const short8*)&Bl[gb0 + k0];
    const short8 vbl1 = *(const short8*)&Bl[gb1 + k0];
    __syncthreads();  // prior iteration's ds_reads complete
    *(short8*)&sAh[sw0] = vah0;
    *(short8*)&sAh[sw1] = vah1;
    *(short8*)&sAl[sw0] = val0;
    *(short8*)&sAl[sw1] = val1;
    *(short8*)&sBh[sw0] = vbh0;
    *(short8*)&sBh[sw1] = vbh1;
    *(short8*)&sBl[sw0] = vbl0;
    *(short8*)&sBl[sw1] = vbl1;
    __syncthreads();  // staging visible

    short8 ah[4], al[4], bh[4], bl[4];
#pragma unroll
    for (int f = 0; f < 4; f++) {
      const int ra = wr * 64 + f * 16 + lar;
      const int ia = ra * 32 + ((lkf ^ ((ra >> 1) & 3)) << 3);
      ah[f] = *(const short8*)&sAh[ia];
      al[f] = *(const short8*)&sAl[ia];
      const int rb = wc * 64 + f * 16 + lar;
      const int ib = rb * 32 + ((lkf ^ ((rb >> 1) & 3)) << 3);
      bh[f] = *(const short8*)&sBh[ib];
      bl[f] = *(const short8*)&sBl[ib];
    }
#pragma unroll
    for (int i = 0; i < 4; i++)
#pragma unroll
      for (int j = 0; j < 4; j++) {
        acc[i][j] = __builtin_amdgcn_mfma_f32_16x16x32_bf16(ah[i], bh[j],
                                                            acc[i][j], 0, 0, 0);
        acc[i][j] = __builtin_amdgcn_mfma_f32_16x16x32_bf16(ah[i], bl[j],
                                                            acc[i][j], 0, 0, 0);
        acc[i][j] = __builtin_amdgcn_mfma_f32_16x16x32_bf16(al[i], bh[j],
                                                            acc[i][j], 0, 0, 0);
      }
  }

#pragma unroll
  for (int i = 0; i < 4; i++)
#pragma unroll
    for (int j = 0; j < 4; j++) {
      const int row = m0 + wr * 64 + i * 16 + (l >> 4) * 4;
      const int col = n0 + wc * 64 + j * 16 + (l & 15);
      const f32x4 v = acc[i][j];
#pragma unroll
      for (int q = 0; q < 4; q++) Cz[(size_t)(row + q) * N + col] = v[q];
    }
}

// ---------------------------------------------------------------------------
// Per-row: finish mobius_matvec (tanh scaling + project), logmap0, beta-split
// into heads with expmap0. One block = one (b,l) row, 768 threads,
// wave w == head w (64 lanes == DH).
// ---------------------------------------------------------------------------
__global__ __launch_bounds__(768) void k_qkv_transform(
    const float* __restrict__ x,
    const float* __restrict__ mq, const float* __restrict__ mk,
    const float* __restrict__ mv,
    float* __restrict__ qh, float* __restrict__ kh, float* __restrict__ vhl,
    float* __restrict__ q2n, float* __restrict__ k2n,
    float* __restrict__ lam1, float beta_ratio) {
  const int t = threadIdx.x;
  const int row = blockIdx.x;  // b*L + l
  const int b = row >> 10, l = row & 1023;
  const int w = t >> 6, lane = t & 63;
  __shared__ float red[12];

  const float xe = x[(size_t)row * Dd + t];
  float s = wred64(xe * xe);
  if (lane == 0) red[w] = s;
  __syncthreads();
  float xn2 = 0.0f;
#pragma unroll
  for (int i = 0; i < 12; i++) xn2 += red[i];
  const float xn = sqrtf(fmaxf(xn2, EPSf * EPSf));
  const float arx = artanh_(fminf(xn, MAXN));

  const float* mptr[3] = {mq, mk, mv};
#pragma unroll
  for (int mi = 0; mi < 3; mi++) {
    const float me = mptr[mi][(size_t)row * Dd + t];
    __syncthreads();  // protect red reuse
    float s2 = wred64(me * me);
    if (lane == 0) red[w] = s2;
    __syncthreads();
    float mn2 = 0.0f;
#pragma unroll
    for (int i = 0; i < 12; i++) mn2 += red[i];
    const float mxn = sqrtf(fmaxf(mn2, EPSf * EPSf));
    const float pn = tanhf(mxn / xn * arx);
    const float c1 = pn / mxn * fminf(1.0f, MAXN / fmaxf(pn, EPSf));
    const float nn = fmaxf(fminf(pn, MAXN), EPSf);
    const float c2 = artanh_(nn) / nn;
    const float ve = c2 * c1 * me * beta_ratio;
    const float hs = wred64(ve * ve);
    const float hn = sqrtf(fmaxf(hs, EPSf * EPSf));
    const float th = tanhf(hn);
    const float oe = th / hn * ve;
    const size_t hidx = (size_t)(b * Hh + w) * Ll + l;
    const size_t oidx = hidx * DHh + lane;
    if (mi == 0) {
      qh[oidx] = oe;
      if (lane == 0) q2n[hidx] = th * th;
    } else if (mi == 1) {
      kh[oidx] = oe;
      if (lane == 0) k2n[hidx] = th * th;
    } else {
      const float lam = 2.0f / fmaxf(1.0f - th * th, EPSf);
      vhl[oidx] = lam * oe;
      if (lane == 0) lam1[hidx] = lam - 1.0f;
    }
  }
}

// ---------------------------------------------------------------------------
// Scores: per (b,h), 64 q-rows per block, stream k in chunks of 64.
// e = exp(-scale * dist) written UNNORMALIZED to attn; row sums to ws.
// ---------------------------------------------------------------------------
__global__ __launch_bounds__(256) void k_scores(
    const float* __restrict__ qh, const float* __restrict__ kh,
    const float* __restrict__ q2n, const float* __restrict__ k2n,
    const float* __restrict__ scale_p,
    float* __restrict__ attn, float* __restrict__ rowsum) {
  __shared__ __align__(16) float Qs[64][68];  // [d][q]
  __shared__ __align__(16) float Ks[64][68];  // [d][k]
  __shared__ float q2s[64], k2s[64];
  const int t = threadIdx.x;
  const int tx = t & 15, ty = t >> 4;
  const int bh = blockIdx.y;
  const int q0 = blockIdx.x * 64;
  const float scale = scale_p[0];
  const size_t hbase = (size_t)bh * Ll;

  {
    const int d = t & 63, rw = t >> 6;
#pragma unroll
    for (int i = 0; i < 16; i++) {
      const int r = (i << 2) + rw;
      Qs[d][r] = qh[(hbase + q0 + r) * DHh + d];
    }
  }
  if (t < 64) q2s[t] = q2n[hbase + q0 + t];

  float rs[4] = {0.0f, 0.0f, 0.0f, 0.0f};
  for (int c = 0; c < 16; c++) {
    __syncthreads();
    {
      const int d = t & 63, rw = t >> 6;
#pragma unroll
      for (int i = 0; i < 16; i++) {
        const int r = (i << 2) + rw;
        Ks[d][r] = kh[(hbase + c * 64 + r) * DHh + d];
      }
      if (t < 64) k2s[t] = k2n[hbase + c * 64 + t];
    }
    __syncthreads();
    float acc[4][4] = {};
#pragma unroll 16
    for (int d = 0; d < 64; d++) {
      float a[4], b[4];
      *(float4*)a = *(const float4*)&Qs[d][ty * 4];
      *(float4*)b = *(const float4*)&Ks[d][tx * 4];
#pragma unroll
      for (int i = 0; i < 4; i++)
#pragma unroll
        for (int j = 0; j < 4; j++)
          acc[i][j] = fmaf(a[i], b[j], acc[i][j]);
    }
#pragma unroll
    for (int i = 0; i < 4; i++) {
      const float q2v = q2s[ty * 4 + i];
      float ev[4];
#pragma unroll
      for (int j = 0; j < 4; j++) {
        const float k2v = k2s[tx * 4 + j];
        const float qk = acc[i][j];
        const float diff2 = fmaxf(q2v + k2v - 2.0f * qk, 0.0f);
        const float den = fmaxf(1.0f - 2.0f * qk + q2v * k2v, EPSf);
        float tt = sqrtf(fmaxf(diff2 / den, 0.0f));
        tt = fminf(tt, MAXN);
        const float e = expf(scale * logf((1.0f - tt) / (1.0f + tt)));
        ev[j] = e;
        rs[i] += e;
      }
      *(float4*)&attn[(hbase + q0 + ty * 4 + i) * Ll + c * 64 + tx * 4] =
          *(float4*)ev;
    }
  }
#pragma unroll
  for (int i = 0; i < 4; i++) {
    float v = rs[i];
    v += __shfl_xor(v, 1, 64);
    v += __shfl_xor(v, 2, 64);
    v += __shfl_xor(v, 4, 64);
    v += __shfl_xor(v, 8, 64);
    if (tx == 0) rowsum[hbase + q0 + ty * 4 + i] = v;
  }
}

// ---------------------------------------------------------------------------
// Midpoint: normalize attn in place, PV GEMM with lam*v and lam-1,
// then mobius_scalar_mul(0.5) + project. Writes yh in (B,L,H,DH) layout.
// ---------------------------------------------------------------------------
__global__ __launch_bounds__(256) void k_midpoint(
    float* __restrict__ attn, const float* __restrict__ vhl,
    const float* __restrict__ lam1, const float* __restrict__ rowsum,
    float* __restrict__ yh) {
  __shared__ __align__(16) float Ws[64][68];  // [k][q]
  __shared__ __align__(16) float Ls[64][68];  // [k][d]
  __shared__ float l1s[64];
  __shared__ float rinv[64];
  const int t = threadIdx.x;
  const int tx = t & 15, ty = t >> 4;
  const int bh = blockIdx.y;
  const int b = bh / Hh, h = bh % Hh;
  const int q0 = blockIdx.x * 64;
  const size_t hbase = (size_t)bh * Ll;
  if (t < 64) rinv[t] = 1.0f / rowsum[hbase + q0 + t];

  float acc[4][4] = {};
  float dacc[4] = {0.0f, 0.0f, 0.0f, 0.0f};
  for (int c = 0; c < 16; c++) {
    __syncthreads();
    {
      const int d = t & 63, rw = t >> 6;
#pragma unroll
      for (int i = 0; i < 16; i++) {
        const int k = (i << 2) + rw;
        Ls[k][d] = vhl[(hbase + c * 64 + k) * DHh + d];
      }
      if (t < 64) l1s[t] = lam1[hbase + c * 64 + t];
#pragma unroll
      for (int i = 0; i < 16; i++) {
        const int q = (i << 2) + rw;
        const size_t gidx = (hbase + q0 + q) * Ll + c * 64 + d;
        const float wv = attn[gidx] * rinv[q];
        attn[gidx] = wv;
        Ws[d][q] = wv;
      }
    }
    __syncthreads();
#pragma unroll 16
    for (int k = 0; k < 64; k++) {
      float a[4], bb[4];
      *(float4*)a = *(const float4*)&Ws[k][ty * 4];
      *(float4*)bb = *(const float4*)&Ls[k][tx * 4];
      const float l1 = l1s[k];
#pragma unroll
      for (int i = 0; i < 4; i++) {
        dacc[i] = fmaf(a[i], l1, dacc[i]);
#pragma unroll
        for (int j = 0; j < 4; j++)
          acc[i][j] = fmaf(a[i], bb[j], acc[i][j]);
      }
    }
  }
#pragma unroll
  for (int i = 0; i < 4; i++) {
    float den = dacc[i];
    if (fabsf(den) < 1e-10f) den = 1e-10f;
    const float dinv = 1.0f / den;
    float tm[4];
    float n2p = 0.0f;
#pragma unroll
    for (int j = 0; j < 4; j++) {
      tm[j] = acc[i][j] * dinv;
      n2p += tm[j] * tm[j];
    }
    n2p += __shfl_xor(n2p, 1, 64);
    n2p += __shfl_xor(n2p, 2, 64);
    n2p += __shfl_xor(n2p, 4, 64);
    n2p += __shfl_xor(n2p, 8, 64);
    const float n = sqrtf(fmaxf(n2p, EPSf * EPSf));
    const float ar = artanh_(fminf(n, MAXN));
    const float pn = tanhf(0.5f * ar);
    const float f = pn / n * fminf(1.0f, MAXN / fmaxf(pn, EPSf));
    float ov[4];
#pragma unroll
    for (int j = 0; j < 4; j++) ov[j] = f * tm[j];
    const int lq = q0 + ty * 4 + i;
    *(float4*)&yh[((size_t)(b * Ll + lq) * Hh + h) * DHh + tx * 4] =
        *(float4*)ov;
  }
}

// ---------------------------------------------------------------------------
// beta_concat: per-head logmap0 / BETA_RATIO, then expmap0 over full D.
// ---------------------------------------------------------------------------
__global__ __launch_bounds__(768) void k_concat(
    const float* __restrict__ yh, float* __restrict__ yc, float beta_ratio) {
  const int t = threadIdx.x;
  const int row = blockIdx.x;
  const int w = t >> 6, lane = t & 63;
  __shared__ float red[12];
  const float ye = yh[(size_t)row * Dd + t];
  const float hs = wred64(ye * ye);
  const float hn = sqrtf(fmaxf(hs, EPSf * EPSf));
  const float cc = artanh_(fminf(hn, MAXN)) / hn / beta_ratio;
  const float ve = cc * ye;
  const float s = wred64(ve * ve);
  if (lane == 0) red[w] = s;
  __syncthreads();
  float n2 = 0.0f;
#pragma unroll
  for (int i = 0; i < 12; i++) n2 += red[i];
  const float n = sqrtf(fmaxf(n2, EPSf * EPSf));
  const float f = tanhf(n) / n;
  yc[(size_t)row * Dd + t] = f * ve;
}

// ---------------------------------------------------------------------------
// Final: mobius_matvec scaling (project), mobius_add with bias, project.
// ---------------------------------------------------------------------------
__global__ __launch_bounds__(768) void k_final(
    const float* __restrict__ yc, const float* __restrict__ mp,
    const float* __restrict__ bp, float* __restrict__ out) {
  const int t = threadIdx.x;
  const int row = blockIdx.x;
  const int w = t >> 6, lane = t & 63;
  __shared__ float red[12];
  auto blockSum = [&](float v) -> float {
    __syncthreads();
    const float s = wred64(v);
    if (lane == 0) red[w] = s;
    __syncthreads();
    float tot = 0.0f;
#pragma unroll
    for (int i = 0; i < 12; i++) tot += red[i];
    return tot;
  };
  const float xe = yc[(size_t)row * Dd + t];
  const float me = mp[(size_t)row * Dd + t];
  const float be = bp[t];
  const float xn2 = blockSum(xe * xe);
  const float xn = sqrtf(fmaxf(xn2, EPSf * EPSf));
  const float arx = artanh_(fminf(xn, MAXN));
  const float mn2 = blockSum(me * me);
  const float mxn = sqrtf(fmaxf(mn2, EPSf * EPSf));
  const float pn = tanhf(mxn / xn * arx);
  const float c1 = pn / mxn * fminf(1.0f, MAXN / fmaxf(pn, EPSf));
  const float mme = c1 * me;
  const float x2 = blockSum(mme * mme);
  const float y2 = blockSum(be * be);
  const float xy = blockSum(mme * be);
  const float nume = (1.0f + 2.0f * xy + y2) * mme + (1.0f - x2) * be;
  const float den = fmaxf(1.0f + 2.0f * xy + x2 * y2, EPSf);
  const float re = nume / den;
  const float rn2 = blockSum(re * re);
  const float rn = sqrtf(fmaxf(rn2, EPSf * EPSf));
  const float f = fminf(1.0f, MAXN / rn);
  out[(size_t)row * Dd + t] = f * re;
}

}  // namespace

extern "C" void kernel_launch(void* const* d_in, const int* in_sizes, int n_in,
                              void* d_out, int out_size, void* d_ws,
                              size_t ws_size, hipStream_t stream) {
  const float* x = (const float*)d_in[0];
  const float* Wq = (const float*)d_in[1];
  const float* Wk = (const float*)d_in[2];
  const float* Wv = (const float*)d_in[3];
  const float* Wp = (const float*)d_in[4];
  const float* bp = (const float*)d_in[5];
  const float* scale = (const float*)d_in[6];

  float* out = (float*)d_out;
  float* y_out = out;                        // (B,L,D)
  float* attn = out + (size_t)Bb * Ll * Dd;  // (B,H,L,L)

  const size_t NH = (size_t)Bb * Hh * Ll;  // 98304
  const size_t RD = (size_t)Bb * Ll * Dd;  // 6291456
  float* ws = (float*)d_ws;
  float* qh = ws;            // RD
  float* kh = qh + RD;       // RD
  float* vhl = kh + RD;      // RD (lam * v)
  float* yh = vhl + RD;      // RD
  float* rowsum = yh + RD;   // NH
  float* q2n = rowsum + NH;  // NH
  float* k2n = q2n + NH;     // NH
  float* lam1 = k2n + NH;    // NH
  unsigned short* whi = (unsigned short*)(lam1 + NH);  // 4*DD shorts
  unsigned short* wlo = whi + 4 * (size_t)DDm;         // 4*DD shorts
  float* yc = qh;  // reuse (qh dead after k_scores)
  float* mp = kh;  // reuse (kh dead after k_scores)

  // GEMM outputs + bf16 copies of x staged in the not-yet-written attn region.
  float* mq = attn;
  float* mk = attn + RD;
  float* mv = attn + 2 * RD;
  unsigned short* xhi = (unsigned short*)(attn + 3 * RD);  // RD shorts
  unsigned short* xlo = xhi + RD;                          // RD shorts
  // yc bf16 copies reuse the vhl region (dead after k_midpoint).
  unsigned short* ychi = (unsigned short*)vhl;
  unsigned short* yclo = ychi + RD;

  const double br =
      exp(lgamma(DHh / 2.0) + lgamma(0.5) - lgamma(DHh / 2.0 + 0.5) -
          (lgamma(Dd / 2.0) + lgamma(0.5) - lgamma(Dd / 2.0 + 0.5)));
  const float beta_ratio = (float)br;

  (void)in_sizes; (void)n_in; (void)out_size; (void)ws_size;

  // Split conversions.
  k_cvt<<<dim3((int)(RD / 4 / 256)), dim3(256), 0, stream>>>(x, xhi, xlo,
                                                             (int)(RD / 4));
  k_cvt<<<dim3(DDm / 4 / 256), dim3(256), 0, stream>>>(Wq, whi, wlo, DDm / 4);
  k_cvt<<<dim3(DDm / 4 / 256), dim3(256), 0, stream>>>(
      Wk, whi + (size_t)DDm, wlo + (size_t)DDm, DDm / 4);
  k_cvt<<<dim3(DDm / 4 / 256), dim3(256), 0, stream>>>(
      Wv, whi + 2 * (size_t)DDm, wlo + 2 * (size_t)DDm, DDm / 4);
  k_cvt<<<dim3(DDm / 4 / 256), dim3(256), 0, stream>>>(
      Wp, whi + 3 * (size_t)DDm, wlo + 3 * (size_t)DDm, DDm / 4);

  // Fused QKV GEMM (MFMA).
  k_gemm_bf16s<<<dim3(Dd / 128, (Bb * Ll) / 128, 3), dim3(256), 0, stream>>>(
      xhi, xlo, whi, wlo, mq);

  k_qkv_transform<<<dim3(Bb * Ll), dim3(768), 0, stream>>>(
      x, mq, mk, mv, qh, kh, vhl, q2n, k2n, lam1, beta_ratio);

  k_scores<<<dim3(16, Bb * Hh), dim3(256), 0, stream>>>(qh, kh, q2n, k2n,
                                                        scale, attn, rowsum);

  k_midpoint<<<dim3(16, Bb * Hh), dim3(256), 0, stream>>>(attn, vhl, lam1,
                                                          rowsum, yh);

  k_concat<<<dim3(Bb * Ll), dim3(768), 0, stream>>>(yh, yc, beta_ratio);

  // Projection GEMM (MFMA).
  k_cvt<<<dim3((int)(RD / 4 / 256)), dim3(256), 0, stream>>>(yc, ychi, yclo,
                                                             (int)(RD / 4));
  k_gemm_bf16s<<<dim3(Dd / 128, (Bb * Ll) / 128, 1), dim3(256), 0, stream>>>(
      ychi, yclo, whi + 3 * (size_t)DDm, wlo + 3 * (size_t)DDm, mp);

  k_final<<<dim3(Bb * Ll), dim3(768), 0, stream>>>(yc, mp, bp, y_out);
}

// Round 3
// 882.323 us; speedup vs baseline: 1.7664x; 1.3038x over previous
//
#include <hip/hip_runtime.h>
#include <hip/hip_bf16.h>
#include <math.h>

namespace {

constexpr int Bb = 8, Ll = 1024, Dd = 768, Hh = 12, DHh = 64;
constexpr int DDm = Dd * Dd;
constexpr float MAXN = 1.0f - 1e-5f;
constexpr float EPSf = 1e-15f;

typedef __attribute__((ext_vector_type(8))) short short8;
typedef __attribute__((ext_vector_type(4))) float f32x4;

__device__ __forceinline__ float wred64(float v) {
#pragma unroll
  for (int m = 32; m >= 1; m >>= 1) v += __shfl_xor(v, m, 64);
  return v;
}

__device__ __forceinline__ float artanh_(float x) {
  return 0.5f * logf((1.0f + x) / (1.0f - x));
}

__device__ __forceinline__ void bsplit(float x, unsigned short& h,
                                       unsigned short& l) {
  __hip_bfloat16 hb = __float2bfloat16(x);
  const float hf = __bfloat162float(hb);
  __hip_bfloat16 lb = __float2bfloat16(x - hf);
  h = *(unsigned short*)&hb;
  l = *(unsigned short*)&lb;
}

// e = exp(-scale * 2*artanh(t)) = ((1-t)/(1+t))^scale ; fast path scale==1
__device__ __forceinline__ float score_e(float qk, float q2v, float k2v,
                                         float scale, bool sone) {
  const float diff2 = fmaxf(q2v + k2v - 2.0f * qk, 0.0f);
  const float den = fmaxf(1.0f - 2.0f * qk + q2v * k2v, EPSf);
  const float r = diff2 * __builtin_amdgcn_rcpf(den);
  const float t = fminf(sqrtf(fmaxf(r, 0.0f)), MAXN);
  const float p = (1.0f - t) * __builtin_amdgcn_rcpf(1.0f + t);
  return sone ? p : expf(scale * logf(p));
}

// ---------------------------------------------------------------------------
// Split fp32 -> bf16 hi + bf16 lo.
// ---------------------------------------------------------------------------
__global__ __launch_bounds__(256) void k_cvt(const float* __restrict__ in,
                                             unsigned short* __restrict__ hi,
                                             unsigned short* __restrict__ lo,
                                             int n4) {
  const int i = blockIdx.x * 256 + threadIdx.x;
  if (i >= n4) return;
  float4 v = ((const float4*)in)[i];
  float xs[4] = {v.x, v.y, v.z, v.w};
  unsigned short hs[4], ls[4];
#pragma unroll
  for (int j = 0; j < 4; j++) bsplit(xs[j], hs[j], ls[j]);
  ((ushort4*)hi)[i] = make_ushort4(hs[0], hs[1], hs[2], hs[3]);
  ((ushort4*)lo)[i] = make_ushort4(ls[0], ls[1], ls[2], ls[3]);
}

// ---------------------------------------------------------------------------
// bf16-split MFMA GEMM: C = A @ W^T (~fp32 precision), as round 1.
// ---------------------------------------------------------------------------
__global__ __launch_bounds__(256) void k_gemm_bf16s(
    const unsigned short* __restrict__ Ahi, const unsigned short* __restrict__ Alo,
    const unsigned short* __restrict__ Whi, const unsigned short* __restrict__ Wlo,
    float* __restrict__ C) {
  constexpr int K = Dd, N = Dd;
  const int z = blockIdx.z;
  const unsigned short* Bh = Whi + (size_t)z * DDm;
  const unsigned short* Bl = Wlo + (size_t)z * DDm;
  float* Cz = C + (size_t)z * 8192 * N;
  __shared__ __align__(16) unsigned short sAh[128 * 32];
  __shared__ __align__(16) unsigned short sAl[128 * 32];
  __shared__ __align__(16) unsigned short sBh[128 * 32];
  __shared__ __align__(16) unsigned short sBl[128 * 32];
  const int t = threadIdx.x;
  const int l = t & 63, wid = t >> 6;
  const int wr = wid >> 1, wc = wid & 1;
  const int m0 = blockIdx.y * 128, n0 = blockIdx.x * 128;

  const int r0 = t >> 2, kf0 = t & 3;
  const int r1 = (t + 256) >> 2, kf1 = (t + 256) & 3;
  const int sw0 = r0 * 32 + ((kf0 ^ ((r0 >> 1) & 3)) << 3);
  const int sw1 = r1 * 32 + ((kf1 ^ ((r1 >> 1) & 3)) << 3);
  const size_t ga0 = (size_t)(m0 + r0) * K + kf0 * 8;
  const size_t ga1 = (size_t)(m0 + r1) * K + kf1 * 8;
  const size_t gb0 = (size_t)(n0 + r0) * K + kf0 * 8;
  const size_t gb1 = (size_t)(n0 + r1) * K + kf1 * 8;

  const int lar = l & 15, lkf = l >> 4;

  f32x4 acc[4][4] = {};

  for (int k0 = 0; k0 < K; k0 += 32) {
    const short8 vah0 = *(const short8*)&Ahi[ga0 + k0];
    const short8 vah1 = *(const short8*)&Ahi[ga1 + k0];
    const short8 val0 = *(const short8*)&Alo[ga0 + k0];
    const short8 val1 = *(const short8*)&Alo[ga1 + k0];
    const short8 vbh0 = *(const short8*)&Bh[gb0 + k0];
    const short8 vbh1 = *(const short8*)&Bh[gb1 + k0];
    const short8 vbl0 = *(const short8*)&Bl[gb0 + k0];
    const short8 vbl1 = *(const short8*)&Bl[gb1 + k0];
    __syncthreads();
    *(short8*)&sAh[sw0] = vah0;
    *(short8*)&sAh[sw1] = vah1;
    *(short8*)&sAl[sw0] = val0;
    *(short8*)&sAl[sw1] = val1;
    *(short8*)&sBh[sw0] = vbh0;
    *(short8*)&sBh[sw1] = vbh1;
    *(short8*)&sBl[sw0] = vbl0;
    *(short8*)&sBl[sw1] = vbl1;
    __syncthreads();

    short8 ah[4], al[4], bh[4], bl[4];
#pragma unroll
    for (int f = 0; f < 4; f++) {
      const int ra = wr * 64 + f * 16 + lar;
      const int ia = ra * 32 + ((lkf ^ ((ra >> 1) & 3)) << 3);
      ah[f] = *(const short8*)&sAh[ia];
      al[f] = *(const short8*)&sAl[ia];
      const int rb = wc * 64 + f * 16 + lar;
      const int ib = rb * 32 + ((lkf ^ ((rb >> 1) & 3)) << 3);
      bh[f] = *(const short8*)&sBh[ib];
      bl[f] = *(const short8*)&sBl[ib];
    }
#pragma unroll
    for (int i = 0; i < 4; i++)
#pragma unroll
      for (int j = 0; j < 4; j++) {
        acc[i][j] = __builtin_amdgcn_mfma_f32_16x16x32_bf16(ah[i], bh[j],
                                                            acc[i][j], 0, 0, 0);
        acc[i][j] = __builtin_amdgcn_mfma_f32_16x16x32_bf16(ah[i], bl[j],
                                                            acc[i][j], 0, 0, 0);
        acc[i][j] = __builtin_amdgcn_mfma_f32_16x16x32_bf16(al[i], bh[j],
                                                            acc[i][j], 0, 0, 0);
      }
  }

#pragma unroll
  for (int i = 0; i < 4; i++)
#pragma unroll
    for (int j = 0; j < 4; j++) {
      const int row = m0 + wr * 64 + i * 16 + (l >> 4) * 4;
      const int col = n0 + wc * 64 + j * 16 + (l & 15);
      const f32x4 v = acc[i][j];
#pragma unroll
      for (int q = 0; q < 4; q++) Cz[(size_t)(row + q) * N + col] = v[q];
    }
}

// ---------------------------------------------------------------------------
// Per-row transform; emits q/k/(lam*v) as bf16 hi/lo + per-head stats.
// ---------------------------------------------------------------------------
__global__ __launch_bounds__(768) void k_qkv_transform(
    const float* __restrict__ x,
    const float* __restrict__ mq, const float* __restrict__ mk,
    const float* __restrict__ mv,
    unsigned short* __restrict__ qhh, unsigned short* __restrict__ qhl,
    unsigned short* __restrict__ khh, unsigned short* __restrict__ khl,
    unsigned short* __restrict__ vhh, unsigned short* __restrict__ vhl_,
    float* __restrict__ q2n, float* __restrict__ k2n,
    float* __restrict__ lam1, float beta_ratio) {
  const int t = threadIdx.x;
  const int row = blockIdx.x;  // b*L + l
  const int b = row >> 10, l = row & 1023;
  const int w = t >> 6, lane = t & 63;
  __shared__ float red[12];

  const float xe = x[(size_t)row * Dd + t];
  float s = wred64(xe * xe);
  if (lane == 0) red[w] = s;
  __syncthreads();
  float xn2 = 0.0f;
#pragma unroll
  for (int i = 0; i < 12; i++) xn2 += red[i];
  const float xn = sqrtf(fmaxf(xn2, EPSf * EPSf));
  const float arx = artanh_(fminf(xn, MAXN));

  const float* mptr[3] = {mq, mk, mv};
#pragma unroll
  for (int mi = 0; mi < 3; mi++) {
    const float me = mptr[mi][(size_t)row * Dd + t];
    __syncthreads();
    float s2 = wred64(me * me);
    if (lane == 0) red[w] = s2;
    __syncthreads();
    float mn2 = 0.0f;
#pragma unroll
    for (int i = 0; i < 12; i++) mn2 += red[i];
    const float mxn = sqrtf(fmaxf(mn2, EPSf * EPSf));
    const float pn = tanhf(mxn / xn * arx);
    const float c1 = pn / mxn * fminf(1.0f, MAXN / fmaxf(pn, EPSf));
    const float nn = fmaxf(fminf(pn, MAXN), EPSf);
    const float c2 = artanh_(nn) / nn;
    const float ve = c2 * c1 * me * beta_ratio;
    const float hs = wred64(ve * ve);
    const float hn = sqrtf(fmaxf(hs, EPSf * EPSf));
    const float th = tanhf(hn);
    const float oe = th / hn * ve;
    const size_t hidx = (size_t)(b * Hh + w) * Ll + l;
    const size_t oidx = hidx * DHh + lane;
    unsigned short hu, lu;
    if (mi == 0) {
      bsplit(oe, hu, lu);
      qhh[oidx] = hu; qhl[oidx] = lu;
      if (lane == 0) q2n[hidx] = th * th;
    } else if (mi == 1) {
      bsplit(oe, hu, lu);
      khh[oidx] = hu; khl[oidx] = lu;
      if (lane == 0) k2n[hidx] = th * th;
    } else {
      const float lam = 2.0f / fmaxf(1.0f - th * th, EPSf);
      bsplit(lam * oe, hu, lu);
      vhh[oidx] = hu; vhl_[oidx] = lu;
      if (lane == 0) lam1[hidx] = lam - 1.0f;
    }
  }
}

// ---------------------------------------------------------------------------
// Transpose lam*v per head: [k][d] -> [d][k] (bf16 hi/lo).
// ---------------------------------------------------------------------------
__global__ __launch_bounds__(256) void k_vt(const unsigned short* __restrict__ vh,
                                            const unsigned short* __restrict__ vl,
                                            unsigned short* __restrict__ th,
                                            unsigned short* __restrict__ tl) {
  __shared__ __align__(16) unsigned short sh[64 * 72];
  __shared__ __align__(16) unsigned short sl[64 * 72];
  const int t = threadIdx.x;
  const int bh = blockIdx.y, c = blockIdx.x;
  const size_t ibase = ((size_t)bh * Ll + c * 64) * DHh;
#pragma unroll
  for (int u = 0; u < 2; u++) {
    const int ch = t + u * 256, r = ch >> 3, f = ch & 7;
    *(short8*)&sh[r * 72 + f * 8] = *(const short8*)&vh[ibase + r * DHh + f * 8];
    *(short8*)&sl[r * 72 + f * 8] = *(const short8*)&vl[ibase + r * DHh + f * 8];
  }
  __syncthreads();
#pragma unroll
  for (int u = 0; u < 2; u++) {
    const int ch = t + u * 256, d = ch >> 3, kb = ch & 7;
    short8 oh, ol;
#pragma unroll
    for (int i = 0; i < 8; i++) {
      oh[i] = (short)sh[(kb * 8 + i) * 72 + d];
      ol[i] = (short)sl[(kb * 8 + i) * 72 + d];
    }
    const size_t ob = ((size_t)bh * DHh + d) * Ll + c * 64 + kb * 8;
    *(short8*)&th[ob] = oh;
    *(short8*)&tl[ob] = ol;
  }
}

// ---------------------------------------------------------------------------
// Pass 1: row sums of unnormalized e (MFMA QK^T + epilogue, no writes of e).
// ---------------------------------------------------------------------------
__global__ __launch_bounds__(256) void k_rowsum(
    const unsigned short* __restrict__ qhh, const unsigned short* __restrict__ qhl,
    const unsigned short* __restrict__ khh, const unsigned short* __restrict__ khl,
    const float* __restrict__ q2n, const float* __restrict__ k2n,
    const float* __restrict__ scale_p, float* __restrict__ rowsum) {
  __shared__ __align__(16) unsigned short kldsh[64 * 72];
  __shared__ __align__(16) unsigned short kldsl[64 * 72];
  __shared__ float k2s[64];
  const int t = threadIdx.x, l = t & 63, w = t >> 6;
  const int lr = l & 15, lg = l >> 4;
  const int bh = blockIdx.y, q0 = blockIdx.x * 64;
  const size_t hbase = (size_t)bh * Ll;
  const float scale = scale_p[0];
  const bool sone = (scale == 1.0f);

  short8 aqh[2], aql[2];
  const int qrow = q0 + w * 16 + lr;
#pragma unroll
  for (int s = 0; s < 2; s++) {
    const size_t off = (hbase + qrow) * (size_t)DHh + s * 32 + lg * 8;
    aqh[s] = *(const short8*)&qhh[off];
    aql[s] = *(const short8*)&qhl[off];
  }
  float q2r[4];
#pragma unroll
  for (int r = 0; r < 4; r++) q2r[r] = q2n[hbase + q0 + w * 16 + lg * 4 + r];

  float rs[4] = {0.0f, 0.0f, 0.0f, 0.0f};
  for (int c = 0; c < 16; c++) {
    __syncthreads();
    {
#pragma unroll
      for (int u = 0; u < 2; u++) {
        const int ch = t + u * 256, r = ch >> 3, f = ch & 7;
        const size_t kg = (hbase + c * 64 + r) * (size_t)DHh + f * 8;
        *(short8*)&kldsh[r * 72 + f * 8] = *(const short8*)&khh[kg];
        *(short8*)&kldsl[r * 72 + f * 8] = *(const short8*)&khl[kg];
      }
      if (t < 64) k2s[t] = k2n[hbase + c * 64 + t];
    }
    __syncthreads();
#pragma unroll
    for (int j = 0; j < 4; j++) {
      f32x4 acc = {};
      const int krow = j * 16 + lr;
#pragma unroll
      for (int s = 0; s < 2; s++) {
        const int ko = krow * 72 + s * 32 + lg * 8;
        const short8 bh8 = *(const short8*)&kldsh[ko];
        const short8 bl8 = *(const short8*)&kldsl[ko];
        acc = __builtin_amdgcn_mfma_f32_16x16x32_bf16(aqh[s], bh8, acc, 0, 0, 0);
        acc = __builtin_amdgcn_mfma_f32_16x16x32_bf16(aqh[s], bl8, acc, 0, 0, 0);
        acc = __builtin_amdgcn_mfma_f32_16x16x32_bf16(aql[s], bh8, acc, 0, 0, 0);
      }
      const float k2v = k2s[j * 16 + lr];
#pragma unroll
      for (int r = 0; r < 4; r++)
        rs[r] += score_e(acc[r], q2r[r], k2v, scale, sone);
    }
  }
#pragma unroll
  for (int r = 0; r < 4; r++) {
    float v = rs[r];
    v += __shfl_xor(v, 1, 64);
    v += __shfl_xor(v, 2, 64);
    v += __shfl_xor(v, 4, 64);
    v += __shfl_xor(v, 8, 64);
    if (lr == 0) rowsum[hbase + q0 + w * 16 + lg * 4 + r] = v;
  }
}

// ---------------------------------------------------------------------------
// Pass 2: recompute e, normalize, write attn; PV via MFMA (split bf16);
// Mobius midpoint epilogue -> yh (B,L,H,DH).
// ---------------------------------------------------------------------------
__global__ __launch_bounds__(256) void k_attn_pv(
    const unsigned short* __restrict__ qhh, const unsigned short* __restrict__ qhl,
    const unsigned short* __restrict__ khh, const unsigned short* __restrict__ khl,
    const unsigned short* __restrict__ vth, const unsigned short* __restrict__ vtl,
    const float* __restrict__ q2n, const float* __restrict__ k2n,
    const float* __restrict__ lam1, const float* __restrict__ rowsum,
    const float* __restrict__ scale_p,
    float* __restrict__ attn, float* __restrict__ yh) {
  __shared__ __align__(16) unsigned short kldsh[64 * 72];
  __shared__ __align__(16) unsigned short kldsl[64 * 72];
  __shared__ __align__(16) unsigned short vldsh[64 * 72];
  __shared__ __align__(16) unsigned short vldsl[64 * 72];
  __shared__ __align__(16) unsigned short wldsh[4][16 * 72];
  __shared__ __align__(16) unsigned short wldsl[4][16 * 72];
  __shared__ float k2s[64], l1s[64];
  const int t = threadIdx.x, l = t & 63, w = t >> 6;
  const int lr = l & 15, lg = l >> 4;
  const int bh = blockIdx.y, q0 = blockIdx.x * 64;
  const size_t hbase = (size_t)bh * Ll;
  const float scale = scale_p[0];
  const bool sone = (scale == 1.0f);

  short8 aqh[2], aql[2];
  const int qrow = q0 + w * 16 + lr;
#pragma unroll
  for (int s = 0; s < 2; s++) {
    const size_t off = (hbase + qrow) * (size_t)DHh + s * 32 + lg * 8;
    aqh[s] = *(const short8*)&qhh[off];
    aql[s] = *(const short8*)&qhl[off];
  }
  float q2r[4], rin[4];
#pragma unroll
  for (int r = 0; r < 4; r++) {
    const size_t qi = hbase + q0 + w * 16 + lg * 4 + r;
    q2r[r] = q2n[qi];
    rin[r] = __builtin_amdgcn_rcpf(rowsum[qi]);
  }
  f32x4 pv[4] = {};
  float dacc[4] = {0.0f, 0.0f, 0.0f, 0.0f};

  for (int c = 0; c < 16; c++) {
    __syncthreads();
    {
#pragma unroll
      for (int u = 0; u < 2; u++) {
        const int ch = t + u * 256, r = ch >> 3, f = ch & 7;
        const size_t kg = (hbase + c * 64 + r) * (size_t)DHh + f * 8;
        *(short8*)&kldsh[r * 72 + f * 8] = *(const short8*)&khh[kg];
        *(short8*)&kldsl[r * 72 + f * 8] = *(const short8*)&khl[kg];
        const size_t vg = ((size_t)bh * DHh + r) * (size_t)Ll + c * 64 + f * 8;
        *(short8*)&vldsh[r * 72 + f * 8] = *(const short8*)&vth[vg];
        *(short8*)&vldsl[r * 72 + f * 8] = *(const short8*)&vtl[vg];
      }
      if (t < 64) {
        k2s[t] = k2n[hbase + c * 64 + t];
        l1s[t] = lam1[hbase + c * 64 + t];
      }
    }
    __syncthreads();
#pragma unroll
    for (int j = 0; j < 4; j++) {
      f32x4 acc = {};
      const int krow = j * 16 + lr;
#pragma unroll
      for (int s = 0; s < 2; s++) {
        const int ko = krow * 72 + s * 32 + lg * 8;
        const short8 bh8 = *(const short8*)&kldsh[ko];
        const short8 bl8 = *(const short8*)&kldsl[ko];
        acc = __builtin_amdgcn_mfma_f32_16x16x32_bf16(aqh[s], bh8, acc, 0, 0, 0);
        acc = __builtin_amdgcn_mfma_f32_16x16x32_bf16(aqh[s], bl8, acc, 0, 0, 0);
        acc = __builtin_amdgcn_mfma_f32_16x16x32_bf16(aql[s], bh8, acc, 0, 0, 0);
      }
      const float k2v = k2s[j * 16 + lr];
      const float l1v = l1s[j * 16 + lr];
#pragma unroll
      for (int r = 0; r < 4; r++) {
        const float e = score_e(acc[r], q2r[r], k2v, scale, sone) * rin[r];
        attn[(hbase + q0 + w * 16 + lg * 4 + r) * (size_t)Ll + c * 64 +
             j * 16 + lr] = e;
        dacc[r] += e * l1v;
        unsigned short eh, el;
        bsplit(e, eh, el);
        wldsh[w][(lg * 4 + r) * 72 + j * 16 + lr] = eh;
        wldsl[w][(lg * 4 + r) * 72 + j * 16 + lr] = el;
      }
    }
    // PV: A = w (16q x 64k), B = lam*v^T staged as [d][k]
#pragma unroll
    for (int s = 0; s < 2; s++) {
      const int ao = lr * 72 + s * 32 + lg * 8;
      const short8 wah = *(const short8*)&wldsh[w][ao];
      const short8 wal = *(const short8*)&wldsl[w][ao];
#pragma unroll
      for (int n = 0; n < 4; n++) {
        const int bo = (n * 16 + lr) * 72 + s * 32 + lg * 8;
        const short8 vbh = *(const short8*)&vldsh[bo];
        const short8 vbl = *(const short8*)&vldsl[bo];
        pv[n] = __builtin_amdgcn_mfma_f32_16x16x32_bf16(wah, vbh, pv[n], 0, 0, 0);
        pv[n] = __builtin_amdgcn_mfma_f32_16x16x32_bf16(wah, vbl, pv[n], 0, 0, 0);
        pv[n] = __builtin_amdgcn_mfma_f32_16x16x32_bf16(wal, vbh, pv[n], 0, 0, 0);
      }
    }
  }

  const int b = bh / Hh, h = bh % Hh;
#pragma unroll
  for (int r = 0; r < 4; r++) {
    float den = dacc[r];
    den += __shfl_xor(den, 1, 64);
    den += __shfl_xor(den, 2, 64);
    den += __shfl_xor(den, 4, 64);
    den += __shfl_xor(den, 8, 64);
    if (fabsf(den) < 1e-10f) den = 1e-10f;
    const float dinv = 1.0f / den;
    float tm[4];
    float n2 = 0.0f;
#pragma unroll
    for (int n = 0; n < 4; n++) {
      tm[n] = pv[n][r] * dinv;
      n2 += tm[n] * tm[n];
    }
    n2 += __shfl_xor(n2, 1, 64);
    n2 += __shfl_xor(n2, 2, 64);
    n2 += __shfl_xor(n2, 4, 64);
    n2 += __shfl_xor(n2, 8, 64);
    const float nn = sqrtf(fmaxf(n2, EPSf * EPSf));
    const float nc = fminf(nn, MAXN);
    // tanh(artanh(nc)/2) = nc / (1 + sqrt(1 - nc^2))
    const float pn = nc / (1.0f + sqrtf(fmaxf(1.0f - nc * nc, 0.0f)));
    const float f = pn / nn * fminf(1.0f, MAXN / fmaxf(pn, EPSf));
    const int ql = q0 + w * 16 + lg * 4 + r;
#pragma unroll
    for (int n = 0; n < 4; n++)
      yh[(((size_t)(b * Ll + ql)) * Hh + h) * DHh + n * 16 + lr] = f * tm[n];
  }
}

// ---------------------------------------------------------------------------
// beta_concat: per-head logmap0 / BETA_RATIO, then expmap0 over full D.
// ---------------------------------------------------------------------------
__global__ __launch_bounds__(768) void k_concat(
    const float* __restrict__ yh, float* __restrict__ yc, float beta_ratio) {
  const int t = threadIdx.x;
  const int row = blockIdx.x;
  const int w = t >> 6, lane = t & 63;
  __shared__ float red[12];
  const float ye = yh[(size_t)row * Dd + t];
  const float hs = wred64(ye * ye);
  const float hn = sqrtf(fmaxf(hs, EPSf * EPSf));
  const float cc = artanh_(fminf(hn, MAXN)) / hn / beta_ratio;
  const float ve = cc * ye;
  const float s = wred64(ve * ve);
  if (lane == 0) red[w] = s;
  __syncthreads();
  float n2 = 0.0f;
#pragma unroll
  for (int i = 0; i < 12; i++) n2 += red[i];
  const float n = sqrtf(fmaxf(n2, EPSf * EPSf));
  const float f = tanhf(n) / n;
  yc[(size_t)row * Dd + t] = f * ve;
}

// ---------------------------------------------------------------------------
// Final: mobius_matvec scaling (project), mobius_add with bias, project.
// ---------------------------------------------------------------------------
__global__ __launch_bounds__(768) void k_final(
    const float* __restrict__ yc, const float* __restrict__ mp,
    const float* __restrict__ bp, float* __restrict__ out) {
  const int t = threadIdx.x;
  const int row = blockIdx.x;
  const int w = t >> 6, lane = t & 63;
  __shared__ float red[12];
  auto blockSum = [&](float v) -> float {
    __syncthreads();
    const float s = wred64(v);
    if (lane == 0) red[w] = s;
    __syncthreads();
    float tot = 0.0f;
#pragma unroll
    for (int i = 0; i < 12; i++) tot += red[i];
    return tot;
  };
  const float xe = yc[(size_t)row * Dd + t];
  const float me = mp[(size_t)row * Dd + t];
  const float be = bp[t];
  const float xn2 = blockSum(xe * xe);
  const float xn = sqrtf(fmaxf(xn2, EPSf * EPSf));
  const float arx = artanh_(fminf(xn, MAXN));
  const float mn2 = blockSum(me * me);
  const float mxn = sqrtf(fmaxf(mn2, EPSf * EPSf));
  const float pn = tanhf(mxn / xn * arx);
  const float c1 = pn / mxn * fminf(1.0f, MAXN / fmaxf(pn, EPSf));
  const float mme = c1 * me;
  const float x2 = blockSum(mme * mme);
  const float y2 = blockSum(be * be);
  const float xy = blockSum(mme * be);
  const float nume = (1.0f + 2.0f * xy + y2) * mme + (1.0f - x2) * be;
  const float den = fmaxf(1.0f + 2.0f * xy + x2 * y2, EPSf);
  const float re = nume / den;
  const float rn2 = blockSum(re * re);
  const float rn = sqrtf(fmaxf(rn2, EPSf * EPSf));
  const float f = fminf(1.0f, MAXN / rn);
  out[(size_t)row * Dd + t] = f * re;
}

}  // namespace

extern "C" void kernel_launch(void* const* d_in, const int* in_sizes, int n_in,
                              void* d_out, int out_size, void* d_ws,
                              size_t ws_size, hipStream_t stream) {
  const float* x = (const float*)d_in[0];
  const float* Wq = (const float*)d_in[1];
  const float* Wk = (const float*)d_in[2];
  const float* Wv = (const float*)d_in[3];
  const float* Wp = (const float*)d_in[4];
  const float* bp = (const float*)d_in[5];
  const float* scale = (const float*)d_in[6];

  float* out = (float*)d_out;
  float* y_out = out;                        // (B,L,D)
  float* attn = out + (size_t)Bb * Ll * Dd;  // (B,H,L,L)

  const size_t NH = (size_t)Bb * Hh * Ll;  // 98304
  const size_t RD = (size_t)Bb * Ll * Dd;  // 6291456

  unsigned short* u = (unsigned short*)d_ws;
  unsigned short* qhh = u;
  unsigned short* qhl = u + RD;
  unsigned short* khh = u + 2 * RD;
  unsigned short* khl = u + 3 * RD;
  unsigned short* vth = u + 4 * RD;
  unsigned short* vtl = u + 5 * RD;
  unsigned short* vhh = u + 6 * RD;  // dead after k_vt
  unsigned short* vhl_ = u + 7 * RD;
  unsigned short* whi = u + 8 * RD;          // 4*DD ushorts
  unsigned short* wlo = whi + 4 * (size_t)DDm;
  float* fb = (float*)(wlo + 4 * (size_t)DDm);
  float* q2n = fb;
  float* k2n = fb + NH;
  float* lam1 = fb + 2 * NH;
  float* rowsum = fb + 3 * NH;
  // overlays (dead-region reuse after k_attn_pv):
  float* yh = (float*)(u + 6 * RD);    // RD floats over vhh/vhl_
  float* yc = (float*)u;               // RD floats over qhh/qhl
  unsigned short* ychi = u + 2 * RD;   // over khh
  unsigned short* yclo = u + 3 * RD;   // over khl
  float* mp = (float*)(u + 4 * RD);    // RD floats over vth/vtl

  // GEMM outputs + bf16 x staged in the not-yet-written attn region.
  float* mq = attn;
  float* mk = attn + RD;
  float* mv = attn + 2 * RD;
  unsigned short* xhi = (unsigned short*)(attn + 3 * RD);
  unsigned short* xlo = xhi + RD;

  const double br =
      exp(lgamma(DHh / 2.0) + lgamma(0.5) - lgamma(DHh / 2.0 + 0.5) -
          (lgamma(Dd / 2.0) + lgamma(0.5) - lgamma(Dd / 2.0 + 0.5)));
  const float beta_ratio = (float)br;

  (void)in_sizes; (void)n_in; (void)out_size; (void)ws_size;

  k_cvt<<<dim3((int)(RD / 4 / 256)), dim3(256), 0, stream>>>(x, xhi, xlo,
                                                             (int)(RD / 4));
  k_cvt<<<dim3(DDm / 4 / 256), dim3(256), 0, stream>>>(Wq, whi, wlo, DDm / 4);
  k_cvt<<<dim3(DDm / 4 / 256), dim3(256), 0, stream>>>(
      Wk, whi + (size_t)DDm, wlo + (size_t)DDm, DDm / 4);
  k_cvt<<<dim3(DDm / 4 / 256), dim3(256), 0, stream>>>(
      Wv, whi + 2 * (size_t)DDm, wlo + 2 * (size_t)DDm, DDm / 4);
  k_cvt<<<dim3(DDm / 4 / 256), dim3(256), 0, stream>>>(
      Wp, whi + 3 * (size_t)DDm, wlo + 3 * (size_t)DDm, DDm / 4);

  k_gemm_bf16s<<<dim3(Dd / 128, (Bb * Ll) / 128, 3), dim3(256), 0, stream>>>(
      xhi, xlo, whi, wlo, mq);

  k_qkv_transform<<<dim3(Bb * Ll), dim3(768), 0, stream>>>(
      x, mq, mk, mv, qhh, qhl, khh, khl, vhh, vhl_, q2n, k2n, lam1,
      beta_ratio);

  k_vt<<<dim3(16, Bb * Hh), dim3(256), 0, stream>>>(vhh, vhl_, vth, vtl);

  k_rowsum<<<dim3(16, Bb * Hh), dim3(256), 0, stream>>>(
      qhh, qhl, khh, khl, q2n, k2n, scale, rowsum);

  k_attn_pv<<<dim3(16, Bb * Hh), dim3(256), 0, stream>>>(
      qhh, qhl, khh, khl, vth, vtl, q2n, k2n, lam1, rowsum, scale, attn, yh);

  k_concat<<<dim3(Bb * Ll), dim3(768), 0, stream>>>(yh, yc, beta_ratio);

  k_cvt<<<dim3((int)(RD / 4 / 256)), dim3(256), 0, stream>>>(yc, ychi, yclo,
                                                             (int)(RD / 4));
  k_gemm_bf16s<<<dim3(Dd / 128, (Bb * Ll) / 128, 1), dim3(256), 0, stream>>>(
      ychi, yclo, whi + 3 * (size_t)DDm, wlo + 3 * (size_t)DDm, mp);

  k_final<<<dim3(Bb * Ll), dim3(768), 0, stream>>>(yc, mp, bp, y_out);
}